// Round 6
// baseline (367.780 us; speedup 1.0000x reference)
//
#include <hip/hip_runtime.h>
#include <math.h>

typedef _Float16 f16;
typedef f16  v8h __attribute__((ext_vector_type(8)));
typedef float v4f __attribute__((ext_vector_type(4)));

#define EPS_LN 1e-6f
#define GELU_K 0.70710678118654752440f   // 1/sqrt(2)
#define LO_SCALE 65536.0f                // 2^16: keeps fp16 lo-part out of denormal range
#define LO_INV   (1.0f/65536.0f)

// ws layout (bytes):
//   [0, 98304)        wf: uint4[kind2][S6][t8][lane64]  (split-fp16 w_x frags: hi | lo*2^16)
//   [98304, 114688)   tn: float[32][128]  (gelu'd token proj, unit-L2, * p*e^alpha)
#define WS_TN 98304

// LDS row stride 216 f16 = 432 B (16B-aligned; bank pattern <=2-way-ish, measured 2% cost)
#define LSTR 216
#define KOFF (64*216)

__device__ __forceinline__ void split16(float v, f16& hi, f16& lo){
  hi = (f16)v;
  lo = (f16)((v - (float)hi) * LO_SCALE);
}

// ---------------- prep: w_x (fp32 [192][128]) -> split-fp16 MFMA B-frag layout ----------------
// B-frag for 16x16x32: lane holds B[k = 32S + 8*(l>>4) + j][n = 16t + (l&15)], j=0..7
__global__ __launch_bounds__(64) void prep_w(const float* __restrict__ wx, uint4* __restrict__ wf){
  const int S = blockIdx.x >> 3, t = blockIdx.x & 7, l = threadIdx.x;
  const int n  = (t << 4) + (l & 15);
  const int k0 = (S << 5) + ((l >> 4) << 3);
  union { v8h v; uint4 u; } H, L;
  #pragma unroll
  for(int j = 0; j < 8; ++j){
    float v = wx[(size_t)(k0 + j)*128 + n];
    f16 h, lo; split16(v, h, lo);
    H.v[j] = h; L.v[j] = lo;
  }
  wf[(0*6 + S)*512 + t*64 + l] = H.u;
  wf[(1*6 + S)*512 + t*64 + l] = L.u;
}

// ---------------- token pipeline (R5-verified) ----------------
__global__ __launch_bounds__(256) void tok_kernel(
    const float* __restrict__ token, const float* __restrict__ p, const float* __restrict__ alpha,
    const float* __restrict__ g1, const float* __restrict__ b1,
    const float* __restrict__ w_tok, const float* __restrict__ b_tok,
    float* __restrict__ tn_out)
{
  __shared__ float ln[768];
  __shared__ float part[256];
  __shared__ float yv[128];
  __shared__ float rs1[4], rs2[4];
  const int b = blockIdx.x;
  const int t = threadIdx.x;
  const int lane = t & 63, wid = t >> 6;
  const float* tok = token + b*768;

  float v0 = tok[t], v1 = tok[t+256], v2 = tok[t+512];
  float s1 = v0+v1+v2, s2 = v0*v0+v1*v1+v2*v2;
  #pragma unroll
  for(int m = 1; m < 64; m <<= 1){ s1 += __shfl_xor(s1,m,64); s2 += __shfl_xor(s2,m,64); }
  if(lane == 0){ rs1[wid] = s1; rs2[wid] = s2; }
  __syncthreads();
  float S1 = rs1[0]+rs1[1]+rs1[2]+rs1[3];
  float S2 = rs2[0]+rs2[1]+rs2[2]+rs2[3];
  float mean = S1*(1.f/768.f);
  float var  = S2*(1.f/768.f) - mean*mean;
  float rstd = rsqrtf(var + EPS_LN);
  ln[t]       = (v0-mean)*rstd*g1[t]       + b1[t];
  ln[t + 256] = (v1-mean)*rstd*g1[t + 256] + b1[t + 256];
  ln[t + 512] = (v2-mean)*rstd*g1[t + 512] + b1[t + 512];
  __syncthreads();

  const int k  = t & 127;
  const int d0 = (t >> 7) * 384;
  const float* wp = w_tok + (size_t)d0*128 + k;
  float a0 = 0.f, a1 = 0.f, a2 = 0.f, a3 = 0.f;
  #pragma unroll 4
  for(int d = 0; d < 384; d += 4){
    a0 = fmaf(ln[d0+d+0], wp[(size_t)(d+0)*128], a0);
    a1 = fmaf(ln[d0+d+1], wp[(size_t)(d+1)*128], a1);
    a2 = fmaf(ln[d0+d+2], wp[(size_t)(d+2)*128], a2);
    a3 = fmaf(ln[d0+d+3], wp[(size_t)(d+3)*128], a3);
  }
  part[t] = (a0+a1)+(a2+a3);
  __syncthreads();
  if(t < 128){
    float y = part[t] + part[t + 128] + b_tok[k];
    y = 0.5f*y*(1.f + erff(y*GELU_K));     // exact gelu
    yv[t] = y;
  }
  __syncthreads();
  float ss = (t < 128) ? yv[t]*yv[t] : 0.f;
  #pragma unroll
  for(int m = 1; m < 64; m <<= 1) ss += __shfl_xor(ss, m, 64);
  if(lane == 0) rs1[wid] = ss;
  __syncthreads();
  float SS = rs1[0]+rs1[1]+rs1[2]+rs1[3];
  float scale = p[b]*expf(alpha[0]) / fmaxf(sqrtf(SS), 1e-12f);
  if(t < 128) tn_out[b*128 + t] = yv[t]*scale;
}

// ---------------- x pipeline: compact-code version of R5's verified structure ----------------
// Block = 64 rows, 4 waves; wave owns cols [32wv,32wv+32), B frags in regs.
// Code-size discipline (R5 post-mortem: I$-stall suspect): mt is a REAL loop,
// no persistent x register array (x re-read from L1/L2), rolled load/store loops.
__global__ __launch_bounds__(256, 2) void x_kernel(
    const float* __restrict__ x, const float* __restrict__ g2, const float* __restrict__ b2,
    const uint4* __restrict__ wf, const float* __restrict__ bx,
    const float* __restrict__ g3, const float* __restrict__ b3,
    const float* __restrict__ tn, float* __restrict__ out)
{
  __shared__ f16   llds[2*64*LSTR];    // [kind2][row64][k192 pad->216] = 54 KB
  __shared__ float pss[4][64], pdt[4][64];

  const int t = threadIdx.x, lane = t & 63, wv = t >> 6;
  const int q = lane & 3, r = lane >> 2;             // lane = 4*r + q
  const size_t row0 = (size_t)blockIdx.x * 64;
  const int bidx = (int)(row0 >> 12);                // 4096 rows per batch
  const int myrow = wv*16 + r;
  const float* xrow = x + (row0 + myrow)*192 + q*48;

  // ---- phase 1a: LN2 stats, streaming (no register array) ----
  float s1 = 0.f, s2 = 0.f;
  #pragma unroll 4
  for(int i = 0; i < 12; ++i){
    float4 v = *(const float4*)(xrow + i*4);
    s1 += (v.x + v.y) + (v.z + v.w);
    s2 = fmaf(v.x,v.x, fmaf(v.y,v.y, fmaf(v.z,v.z, fmaf(v.w,v.w, s2))));
  }
  s1 += __shfl_xor(s1,1,64); s1 += __shfl_xor(s1,2,64);
  s2 += __shfl_xor(s2,1,64); s2 += __shfl_xor(s2,2,64);
  const float mu   = s1 * (1.f/192.f);
  const float var  = s2 * (1.f/192.f) - mu*mu;
  const float rstd = rsqrtf(var + EPS_LN);

  // ---- phase 1b: ln -> split-fp16 -> LDS (x re-read, L1/L2-hot) ----
  {
    const float* g2p = g2 + q*48;
    const float* b2p = b2 + q*48;
    const int base = myrow*LSTR + q*48;
    #pragma unroll 1
    for(int i = 0; i < 48; i += 8){
      float4 xa = *(const float4*)(xrow + i);
      float4 xb = *(const float4*)(xrow + i + 4);
      float4 ga = *(const float4*)(g2p + i);
      float4 gb = *(const float4*)(g2p + i + 4);
      float4 ba = *(const float4*)(b2p + i);
      float4 bb = *(const float4*)(b2p + i + 4);
      float lv0 = (xa.x-mu)*rstd*ga.x + ba.x;
      float lv1 = (xa.y-mu)*rstd*ga.y + ba.y;
      float lv2 = (xa.z-mu)*rstd*ga.z + ba.z;
      float lv3 = (xa.w-mu)*rstd*ga.w + ba.w;
      float lv4 = (xb.x-mu)*rstd*gb.x + bb.x;
      float lv5 = (xb.y-mu)*rstd*gb.y + bb.y;
      float lv6 = (xb.z-mu)*rstd*gb.z + bb.z;
      float lv7 = (xb.w-mu)*rstd*gb.w + bb.w;
      union { v8h v; uint4 u; } H, L;
      f16 h, lo;
      split16(lv0,h,lo); H.v[0]=h; L.v[0]=lo;
      split16(lv1,h,lo); H.v[1]=h; L.v[1]=lo;
      split16(lv2,h,lo); H.v[2]=h; L.v[2]=lo;
      split16(lv3,h,lo); H.v[3]=h; L.v[3]=lo;
      split16(lv4,h,lo); H.v[4]=h; L.v[4]=lo;
      split16(lv5,h,lo); H.v[5]=h; L.v[5]=lo;
      split16(lv6,h,lo); H.v[6]=h; L.v[6]=lo;
      split16(lv7,h,lo); H.v[7]=h; L.v[7]=lo;
      *(uint4*)&llds[       base + i] = H.u;
      *(uint4*)&llds[KOFF + base + i] = L.u;
    }
  }

  // ---- B frags: loaded after LDS writes; latency hidden by the barrier ----
  v8h Bh[6][2], Bl[6][2];
  #pragma unroll
  for(int S = 0; S < 6; ++S){
    #pragma unroll
    for(int u = 0; u < 2; ++u){
      Bh[S][u] = *(const v8h*)&wf[(0*6 + S)*512 + (2*wv + u)*64 + lane];
      Bl[S][u] = *(const v8h*)&wf[(1*6 + S)*512 + (2*wv + u)*64 + lane];
    }
  }
  __syncthreads();

  // ---- MFMA + epilogue, mt as a REAL loop (code size) ----
  const int n0 = lane & 15, quad = lane >> 4;
  const float* tnb = tn + bidx*128;
  const int col0 = n0 + 16*(2*wv);
  const float bx0 = bx[col0],  bx1 = bx[col0 + 16];
  const float tn0 = tnb[col0], tn1 = tnb[col0 + 16];
  #pragma unroll 1
  for(int mt = 0; mt < 4; ++mt){
    v4f c1a = (v4f){0,0,0,0}, c1b = (v4f){0,0,0,0};
    v4f c2a = (v4f){0,0,0,0}, c2b = (v4f){0,0,0,0};
    const int ab0 = (mt*16 + n0)*LSTR + quad*8;
    #pragma unroll
    for(int S = 0; S < 6; ++S){
      v8h ah = *(v8h*)&llds[ab0 + S*32];
      v8h al = *(v8h*)&llds[KOFF + ab0 + S*32];
      c1a = __builtin_amdgcn_mfma_f32_16x16x32_f16(ah, Bh[S][0], c1a, 0, 0, 0);
      c2a = __builtin_amdgcn_mfma_f32_16x16x32_f16(al, Bh[S][0], c2a, 0, 0, 0);
      c2a = __builtin_amdgcn_mfma_f32_16x16x32_f16(ah, Bl[S][0], c2a, 0, 0, 0);
      c1b = __builtin_amdgcn_mfma_f32_16x16x32_f16(ah, Bh[S][1], c1b, 0, 0, 0);
      c2b = __builtin_amdgcn_mfma_f32_16x16x32_f16(al, Bh[S][1], c2b, 0, 0, 0);
      c2b = __builtin_amdgcn_mfma_f32_16x16x32_f16(ah, Bl[S][1], c2b, 0, 0, 0);
    }
    // C/D layout: (lane, reg g) = D[row = mt*16 + 4*quad + g][col = n0 + 16*tt]
    float ssv[4], dtv[4];
    #pragma unroll
    for(int g = 0; g < 4; ++g){
      float y0 = fmaf(c2a[g], LO_INV, c1a[g]) + bx0;
      y0 = 0.5f*y0*(1.f + erff(y0*GELU_K));
      float y1 = fmaf(c2b[g], LO_INV, c1b[g]) + bx1;
      y1 = 0.5f*y1*(1.f + erff(y1*GELU_K));
      ssv[g] = fmaf(y0, y0,  y1*y1);
      dtv[g] = fmaf(y0, tn0, y1*tn1);
    }
    #pragma unroll
    for(int g = 0; g < 4; ++g){
      #pragma unroll
      for(int m = 1; m < 16; m <<= 1){
        ssv[g] += __shfl_xor(ssv[g], m, 64);
        dtv[g] += __shfl_xor(dtv[g], m, 64);
      }
    }
    if(n0 == 0){
      #pragma unroll
      for(int g = 0; g < 4; ++g){
        pss[wv][mt*16 + quad*4 + g] = ssv[g];
        pdt[wv][mt*16 + quad*4 + g] = dtv[g];
      }
    }
  }
  __syncthreads();

  // ---- attn per row, LN3 via LN2 moments, store (x re-read, L2-hot) ----
  const float SSt = pss[0][myrow] + pss[1][myrow] + pss[2][myrow] + pss[3][myrow];
  const float DTt = pdt[0][myrow] + pdt[1][myrow] + pdt[2][myrow] + pdt[3][myrow];
  const float attn = DTt / fmaxf(sqrtf(SSt), 1e-12f);
  const float rd = rsqrtf(attn*attn*var + EPS_LN);   // mean(a*x)=a*mu, var(a*x)=a^2*var
  const float am = attn * rd;
  const float* g3p = g3 + q*48;
  const float* b3p = b3 + q*48;
  float* orow = out + (row0 + myrow)*192 + q*48;
  #pragma unroll 2
  for(int i = 0; i < 12; ++i){
    float4 xv = *(const float4*)(xrow + i*4);
    float4 gv = *(const float4*)(g3p + i*4);
    float4 bv = *(const float4*)(b3p + i*4);
    float4 o;
    o.x = fmaf(0.5f, xv.x, fmaf(am*(xv.x-mu), gv.x, bv.x));
    o.y = fmaf(0.5f, xv.y, fmaf(am*(xv.y-mu), gv.y, bv.y));
    o.z = fmaf(0.5f, xv.z, fmaf(am*(xv.z-mu), gv.z, bv.z));
    o.w = fmaf(0.5f, xv.w, fmaf(am*(xv.w-mu), gv.w, bv.w));
    *(float4*)(orow + i*4) = o;
  }
}

extern "C" void kernel_launch(void* const* d_in, const int* in_sizes, int n_in,
                              void* d_out, int out_size, void* d_ws, size_t ws_size,
                              hipStream_t stream) {
  const float* x     = (const float*)d_in[0];
  const float* token = (const float*)d_in[1];
  const float* p     = (const float*)d_in[2];
  const float* alpha = (const float*)d_in[3];
  const float* g1    = (const float*)d_in[4];
  const float* b1    = (const float*)d_in[5];
  const float* wtok  = (const float*)d_in[6];
  const float* btok  = (const float*)d_in[7];
  const float* g2    = (const float*)d_in[8];
  const float* b2    = (const float*)d_in[9];
  const float* wx    = (const float*)d_in[10];
  const float* bx    = (const float*)d_in[11];
  const float* g3    = (const float*)d_in[12];
  const float* b3    = (const float*)d_in[13];

  uint4* wf = (uint4*)d_ws;
  float* tn = (float*)((char*)d_ws + WS_TN);
  float* outf = (float*)d_out;

  prep_w<<<48, 64, 0, stream>>>(wx, wf);
  tok_kernel<<<32, 256, 0, stream>>>(token, p, alpha, g1, b1, wtok, btok, tn);
  x_kernel<<<2048, 256, 0, stream>>>(x, g2, b2, wf, bx, g3, b3, tn, outf);
}